// Round 9
// baseline (500.353 us; speedup 1.0000x reference)
//
#include <hip/hip_runtime.h>
#include <hip/hip_fp16.h>

// ---------------------------------------------------------------------------
// GIN forward: 4x [agg(sum) -> Linear+ReLU -> Linear (+ReLU)] -> mean-pool -> head
// N_NODES=50000, N_EDGES=640000, D=128, N_GRAPHS=64, N_CLASSES=32
// R21: R20 minus counter padding (CSTRIDE=16 was a null for build1 -- atomic
//      histogram is rate/latency-bound, not line-contention-bound -- and the
//      prime suspect for the layer FETCH 65->91MB regression), plus pool2
//      fused into the last gin_layer via last-block-done (threadfence +
//      donecnt atomic; the closing block computes counts, pooled, logits
//      with pool2's exact accumulation order). Dispatches 9 -> 8.
//      Layer kernel: exact R14 compute (43.2us/layer at gather ceiling).
// ---------------------------------------------------------------------------

typedef short short8 __attribute__((ext_vector_type(8)));
typedef float floatx4 __attribute__((ext_vector_type(4)));

#define TM 32
#define ZSTRIDE 136   // shorts per row (128 + 8 pad); rows 16B-aligned

__device__ __forceinline__ unsigned short f2bf(float x) {
    unsigned int u = __float_as_uint(x);
    u += 0x7fffu + ((u >> 16) & 1u);          // RNE
    return (unsigned short)(u >> 16);
}
__device__ __forceinline__ float bf2f(unsigned short h) {
    return __uint_as_float(((unsigned int)h) << 16);
}

// fp16 row load: row id, this lane's 4-byte (2-col) slice; fp32 unpack
__device__ __forceinline__ float2 ldrowh(const char* __restrict__ base,
                                         int id, unsigned laneoff) {
    __half2 h = *(const __half2*)(base + ((unsigned)id << 8) + laneoff);
    return __half22float2(h);
}

__device__ __forceinline__ int lb_search(const int* __restrict__ a, int n, int key) {
    int lo = 0, hi = n;
    while (lo < hi) {
        int m = (lo + hi) >> 1;
        if (a[m] < key) lo = m + 1; else hi = m;
    }
    return lo;
}

// ---------------- build 1: weight split + dst histogram(+rank) + x->fp16 -----
// Wf[mat][kc(4)][ct(8)][lane(64)][j(8)] = W[kc*32+(lane>>4)*8+j][ct*16+(lane&15)]

__global__ __launch_bounds__(256) void gin_build1(
    const int* __restrict__ dst, int nEdges, int* __restrict__ counts,
    int* __restrict__ rank,
    const float* __restrict__ w1, const float* __restrict__ w2,
    unsigned short* __restrict__ whf, unsigned short* __restrict__ wlf, int wTotal,
    const float* __restrict__ x, __half* __restrict__ xh, int nNodes) {
    const int gsize = gridDim.x * 256;
    const int gtid = blockIdx.x * 256 + threadIdx.x;
    for (int idx = gtid; idx < wTotal; idx += gsize) {
        int mat  = idx >> 14;
        int rem  = idx & 16383;
        int kc   = rem >> 12;
        int ct   = (rem >> 9) & 7;
        int lane = (rem >> 3) & 63;
        int j    = rem & 7;
        int row = kc * 32 + (lane >> 4) * 8 + j;
        int col = ct * 16 + (lane & 15);
        int L = mat >> 1;
        const float* W = (mat & 1) ? (w2 + (size_t)L * 16384) : (w1 + (size_t)L * 16384);
        float v = W[row * 128 + col];
        unsigned short h = f2bf(v);
        unsigned short l = f2bf(v - bf2f(h));
        whf[idx] = h;
        wlf[idx] = l;
    }
    // x -> fp16 (one-time; layer 0 gathers from xh)
    const int total4 = nNodes * 32;                 // float4 quads
    for (int i = gtid; i < total4; i += gsize) {
        float4 v = ((const float4*)x)[i];
        union { __half2 h[2]; float2 f; } u;
        u.h[0] = __halves2half2(__float2half_rn(v.x), __float2half_rn(v.y));
        u.h[1] = __halves2half2(__float2half_rn(v.z), __float2half_rn(v.w));
        ((float2*)xh)[i] = u.f;
    }
    // histogram; returned old count = edge's rank within its dst segment
    for (int i = gtid; i < nEdges; i += gsize)
        rank[i] = atomicAdd(&counts[dst[i]], 1);
}

// ---------------- build 2a: per-chunk exclusive scan (chunk = 256) -----------

__global__ __launch_bounds__(256) void gin_scanA(const int* __restrict__ counts,
                                                 int* __restrict__ offsLocal,
                                                 int* __restrict__ partials, int n) {
    __shared__ int s[256];
    int t = threadIdx.x;
    int i = blockIdx.x * 256 + t;
    int v = (i < n) ? counts[i] : 0;
    s[t] = v;
    __syncthreads();
    for (int off = 1; off < 256; off <<= 1) {
        int u = (t >= off) ? s[t - off] : 0;
        __syncthreads();
        s[t] += u;
        __syncthreads();
    }
    if (i < n) offsLocal[i] = s[t] - v;        // block-local exclusive
    if (t == 255) partials[blockIdx.x] = s[255];
}

// ---------------- build 2b+3 fused: chunk bases + atomic-free scatter --------
// Every block redundantly scans partials[0..nb) in LDS for chunk bases.
// Scatter: pos = offsLocal[dst] + base[dst>>8] + rank. First nb blocks also
// write the finalized offsets into offsFinal (separate array -> no race).

__global__ __launch_bounds__(256) void gin_scatfuse(
    const int* __restrict__ src, const int* __restrict__ dst,
    const int* __restrict__ rank, int nEdges,
    const int* __restrict__ offsLocal, const int* __restrict__ partials,
    int nb, int* __restrict__ offsFinal, int* __restrict__ ssrc, int nNodes) {
    __shared__ int s[256];
    __shared__ int base[256];
    int t = threadIdx.x;
    s[t] = (t < nb) ? partials[t] : 0;
    __syncthreads();
    for (int off = 1; off < 256; off <<= 1) {
        int u = (t >= off) ? s[t - off] : 0;
        __syncthreads();
        s[t] += u;
        __syncthreads();
    }
    base[t] = (t > 0) ? s[t - 1] : 0;          // exclusive chunk bases
    __syncthreads();

    int i = blockIdx.x * 256 + t;
    if (i < nEdges) {
        int d = dst[i];
        int p = offsLocal[d] + base[d >> 8] + rank[i];
        ssrc[p] = src[i];
    }
    if (blockIdx.x < (unsigned)nb) {
        int j = blockIdx.x * 256 + t;
        if (j < nNodes) offsFinal[j] = offsLocal[j] + base[blockIdx.x];
        if (j == 0) offsFinal[nNodes] = nEdges;
    }
}

// ---------------- fused layer: agg -> MLP (TM=32, 256 thr, 4 waves) ----------
// EXACT R14 compute. Wave w gathers rows w*8..w*8+7 (2-node interleave, 8
// fp16 row-loads in flight, fp32 accumulate), then owns coltiles 2w,2w+1.
// z / y1 live as bf16 hi/lo LDS planes (stride 136 shorts). Last layer pools
// into gsums, then the LAST block to finish (donecnt) runs the classifier
// head (pool2's exact math/order) -- pool2 dispatch eliminated.

__global__ __launch_bounds__(256) void gin_layer(const __half* __restrict__ hin,
                                                 const int* __restrict__ offs,
                                                 const int* __restrict__ ssrc,
                                                 const unsigned short* __restrict__ whf,
                                                 const unsigned short* __restrict__ wlf,
                                                 int matBase,
                                                 const float* __restrict__ b1p,
                                                 const float* __restrict__ b2p,
                                                 __half* __restrict__ hout,
                                                 const int* __restrict__ batch,
                                                 float* __restrict__ gsums,
                                                 int* __restrict__ donecnt,
                                                 const float* __restrict__ wlin,
                                                 const float* __restrict__ blin,
                                                 float* __restrict__ out,
                                                 int nGraphs,
                                                 int nNodes, int lastLayer) {
    __shared__ unsigned short smem[2 * TM * ZSTRIDE];   // hi plane, lo plane
    __shared__ float cntS[128];
    __shared__ int amLast;
    unsigned short* zh = smem;
    unsigned short* zl = smem + TM * ZSTRIDE;
    const int tid = threadIdx.x;
    const int w = tid >> 6, lane = tid & 63;
    const int lo4 = lane & 15, hi4 = lane >> 4;
    const int rowbase = blockIdx.x * TM;
    const char* hbase = (const char*)hin;
    const unsigned laneoff = (unsigned)lane * 4u;

    // ---- gather phase: wave w computes z rows w*8..w*8+7, 2 interleaved
    const int gbase = rowbase + w * 8;
#pragma unroll
    for (int pp = 0; pp < 4; ++pp) {
        int nA = gbase + 2 * pp, nB = nA + 1;
        bool okA = nA < nNodes, okB = nB < nNodes;
        float2 aA = make_float2(0.f, 0.f), aB = make_float2(0.f, 0.f);
        if (okA) aA = ldrowh(hbase, nA, laneoff);
        if (okB) aB = ldrowh(hbase, nB, laneoff);
        int eA = okA ? offs[nA] : 0, endA = okA ? offs[nA + 1] : 0;
        int eB = okB ? offs[nB] : 0, endB = okB ? offs[nB + 1] : 0;

        while (eA + 4 <= endA && eB + 4 <= endB) {
            int sA0 = ssrc[eA], sA1 = ssrc[eA + 1], sA2 = ssrc[eA + 2], sA3 = ssrc[eA + 3];
            int sB0 = ssrc[eB], sB1 = ssrc[eB + 1], sB2 = ssrc[eB + 2], sB3 = ssrc[eB + 3];
            float2 vA0 = ldrowh(hbase, sA0, laneoff);
            float2 vA1 = ldrowh(hbase, sA1, laneoff);
            float2 vA2 = ldrowh(hbase, sA2, laneoff);
            float2 vA3 = ldrowh(hbase, sA3, laneoff);
            float2 vB0 = ldrowh(hbase, sB0, laneoff);
            float2 vB1 = ldrowh(hbase, sB1, laneoff);
            float2 vB2 = ldrowh(hbase, sB2, laneoff);
            float2 vB3 = ldrowh(hbase, sB3, laneoff);
            aA.x += (vA0.x + vA1.x) + (vA2.x + vA3.x);
            aA.y += (vA0.y + vA1.y) + (vA2.y + vA3.y);
            aB.x += (vB0.x + vB1.x) + (vB2.x + vB3.x);
            aB.y += (vB0.y + vB1.y) + (vB2.y + vB3.y);
            eA += 4; eB += 4;
        }
        for (; eA + 4 <= endA; eA += 4) {
            int s0 = ssrc[eA], s1 = ssrc[eA + 1], s2 = ssrc[eA + 2], s3 = ssrc[eA + 3];
            float2 v0 = ldrowh(hbase, s0, laneoff);
            float2 v1 = ldrowh(hbase, s1, laneoff);
            float2 v2 = ldrowh(hbase, s2, laneoff);
            float2 v3 = ldrowh(hbase, s3, laneoff);
            aA.x += (v0.x + v1.x) + (v2.x + v3.x);
            aA.y += (v0.y + v1.y) + (v2.y + v3.y);
        }
        for (; eA < endA; ++eA) {
            float2 v = ldrowh(hbase, ssrc[eA], laneoff);
            aA.x += v.x; aA.y += v.y;
        }
        for (; eB + 4 <= endB; eB += 4) {
            int s0 = ssrc[eB], s1 = ssrc[eB + 1], s2 = ssrc[eB + 2], s3 = ssrc[eB + 3];
            float2 v0 = ldrowh(hbase, s0, laneoff);
            float2 v1 = ldrowh(hbase, s1, laneoff);
            float2 v2 = ldrowh(hbase, s2, laneoff);
            float2 v3 = ldrowh(hbase, s3, laneoff);
            aB.x += (v0.x + v1.x) + (v2.x + v3.x);
            aB.y += (v0.y + v1.y) + (v2.y + v3.y);
        }
        for (; eB < endB; ++eB) {
            float2 v = ldrowh(hbase, ssrc[eB], laneoff);
            aB.x += v.x; aB.y += v.y;
        }
        // write z (cols 2*lane, 2*lane+1) as one u32 per plane per row
        int rA = nA - rowbase, rB = rA + 1;
        unsigned short hx = f2bf(aA.x), hy = f2bf(aA.y);
        ((unsigned int*)zh)[rA * (ZSTRIDE / 2) + lane] = (unsigned)hx | ((unsigned)hy << 16);
        ((unsigned int*)zl)[rA * (ZSTRIDE / 2) + lane] =
            (unsigned)f2bf(aA.x - bf2f(hx)) | ((unsigned)f2bf(aA.y - bf2f(hy)) << 16);
        hx = f2bf(aB.x); hy = f2bf(aB.y);
        ((unsigned int*)zh)[rB * (ZSTRIDE / 2) + lane] = (unsigned)hx | ((unsigned)hy << 16);
        ((unsigned int*)zl)[rB * (ZSTRIDE / 2) + lane] =
            (unsigned)f2bf(aB.x - bf2f(hx)) | ((unsigned)f2bf(aB.y - bf2f(hy)) << 16);
    }
    __syncthreads();

    // ---- MLP phase 1: y1 = relu(z @ W1 + b1); wave w owns coltiles 2w,2w+1
    floatx4 acc[2][2];
#pragma unroll
    for (int rg = 0; rg < 2; ++rg)
#pragma unroll
        for (int ct = 0; ct < 2; ++ct) acc[rg][ct] = (floatx4)0.f;

    for (int kc = 0; kc < 4; ++kc) {
        size_t o0 = ((((size_t)matBase * 4 + kc) * 8 + (2 * w)) * 64 + lane) * 8;
        size_t o1 = ((((size_t)matBase * 4 + kc) * 8 + (2 * w + 1)) * 64 + lane) * 8;
        short8 bh0 = *(const short8*)(whf + o0), bl0 = *(const short8*)(wlf + o0);
        short8 bh1 = *(const short8*)(whf + o1), bl1 = *(const short8*)(wlf + o1);
#pragma unroll
        for (int rg = 0; rg < 2; ++rg) {
            const int rbase = (rg * 16 + lo4) * ZSTRIDE + kc * 32 + hi4 * 8;
            short8 ah = *(const short8*)(zh + rbase);
            short8 al = *(const short8*)(zl + rbase);
            acc[rg][0] = __builtin_amdgcn_mfma_f32_16x16x32_bf16(ah, bh0, acc[rg][0], 0, 0, 0);
            acc[rg][0] = __builtin_amdgcn_mfma_f32_16x16x32_bf16(al, bh0, acc[rg][0], 0, 0, 0);
            acc[rg][0] = __builtin_amdgcn_mfma_f32_16x16x32_bf16(ah, bl0, acc[rg][0], 0, 0, 0);
            acc[rg][1] = __builtin_amdgcn_mfma_f32_16x16x32_bf16(ah, bh1, acc[rg][1], 0, 0, 0);
            acc[rg][1] = __builtin_amdgcn_mfma_f32_16x16x32_bf16(al, bh1, acc[rg][1], 0, 0, 0);
            acc[rg][1] = __builtin_amdgcn_mfma_f32_16x16x32_bf16(ah, bl1, acc[rg][1], 0, 0, 0);
        }
    }
    __syncthreads();   // all z reads done; planes reusable for y1

    // epilogue 1: bias + relu + split -> zh/zl (y1)
    float bb1_0 = b1p[w * 32 + lo4];
    float bb1_1 = b1p[w * 32 + 16 + lo4];
#pragma unroll
    for (int rg = 0; rg < 2; ++rg)
#pragma unroll
        for (int ct = 0; ct < 2; ++ct) {
            float bb = ct ? bb1_1 : bb1_0;
#pragma unroll
            for (int r = 0; r < 4; ++r) {
                float v = fmaxf(acc[rg][ct][r] + bb, 0.f);
                unsigned short h = f2bf(v);
                int idx = (rg * 16 + hi4 * 4 + r) * ZSTRIDE + w * 32 + ct * 16 + lo4;
                zh[idx] = h;
                zl[idx] = f2bf(v - bf2f(h));
            }
        }
    __syncthreads();

    // ---- MLP phase 2: h = y1 @ W2 + b2
#pragma unroll
    for (int rg = 0; rg < 2; ++rg)
#pragma unroll
        for (int ct = 0; ct < 2; ++ct) acc[rg][ct] = (floatx4)0.f;

    for (int kc = 0; kc < 4; ++kc) {
        size_t o0 = ((((size_t)(matBase + 1) * 4 + kc) * 8 + (2 * w)) * 64 + lane) * 8;
        size_t o1 = ((((size_t)(matBase + 1) * 4 + kc) * 8 + (2 * w + 1)) * 64 + lane) * 8;
        short8 bh0 = *(const short8*)(whf + o0), bl0 = *(const short8*)(wlf + o0);
        short8 bh1 = *(const short8*)(whf + o1), bl1 = *(const short8*)(wlf + o1);
#pragma unroll
        for (int rg = 0; rg < 2; ++rg) {
            const int rbase = (rg * 16 + lo4) * ZSTRIDE + kc * 32 + hi4 * 8;
            short8 ah = *(const short8*)(zh + rbase);
            short8 al = *(const short8*)(zl + rbase);
            acc[rg][0] = __builtin_amdgcn_mfma_f32_16x16x32_bf16(ah, bh0, acc[rg][0], 0, 0, 0);
            acc[rg][0] = __builtin_amdgcn_mfma_f32_16x16x32_bf16(al, bh0, acc[rg][0], 0, 0, 0);
            acc[rg][0] = __builtin_amdgcn_mfma_f32_16x16x32_bf16(ah, bl0, acc[rg][0], 0, 0, 0);
            acc[rg][1] = __builtin_amdgcn_mfma_f32_16x16x32_bf16(ah, bh1, acc[rg][1], 0, 0, 0);
            acc[rg][1] = __builtin_amdgcn_mfma_f32_16x16x32_bf16(al, bh1, acc[rg][1], 0, 0, 0);
            acc[rg][1] = __builtin_amdgcn_mfma_f32_16x16x32_bf16(ah, bl1, acc[rg][1], 0, 0, 0);
        }
    }

    float bb2_0 = b2p[w * 32 + lo4];
    float bb2_1 = b2p[w * 32 + 16 + lo4];

    if (!lastLayer) {
#pragma unroll
        for (int rg = 0; rg < 2; ++rg)
#pragma unroll
            for (int ct = 0; ct < 2; ++ct) {
                float bb = ct ? bb2_1 : bb2_0;
#pragma unroll
                for (int r = 0; r < 4; ++r) {
                    int row = rowbase + rg * 16 + hi4 * 4 + r;
                    if (row < nNodes) {
                        float v = fmaxf(acc[rg][ct][r] + bb, 0.f);
                        hout[(size_t)row * 128 + w * 32 + ct * 16 + lo4] = __float2half_rn(v);
                    }
                }
            }
    } else {
        // last layer: no relu; pool tile into gsums (h never hits HBM)
        __syncthreads();   // all y1 reads done; reuse smem as fp32 h (stride 132)
        float* zf = (float*)smem;
#pragma unroll
        for (int rg = 0; rg < 2; ++rg)
#pragma unroll
            for (int ct = 0; ct < 2; ++ct) {
                float bb = ct ? bb2_1 : bb2_0;
#pragma unroll
                for (int r = 0; r < 4; ++r)
                    zf[(rg * 16 + hi4 * 4 + r) * 132 + w * 32 + ct * 16 + lo4] =
                        acc[rg][ct][r] + bb;
            }
        __syncthreads();
        int c = tid & 127, half = tid >> 7;
        int rmax = nNodes - rowbase;
        if (rmax > TM) rmax = TM;
        float accp = 0.f;
        int gcur = -1;
        for (int r = half; r < rmax; r += 2) {
            int g = batch[rowbase + r];
            if (g != gcur) {
                if (gcur >= 0) atomicAdd(&gsums[gcur * 128 + c], accp);
                accp = 0.f;
                gcur = g;
            }
            accp += zf[r * 132 + c];
        }
        if (gcur >= 0) atomicAdd(&gsums[gcur * 128 + c], accp);

        // ---- last-block-done classifier head (replaces gin_pool2 dispatch)
        __threadfence();
        if (tid == 0)
            amLast = (atomicAdd(donecnt, 1) == (int)gridDim.x - 1);
        __syncthreads();
        if (amLast) {
            __threadfence();   // acquire all gsums updates
            for (int g = tid; g < nGraphs; g += 256) {
                int s = lb_search(batch, nNodes, g);
                int e = lb_search(batch, nNodes, g + 1);
                cntS[g] = fmaxf((float)(e - s), 1.0f);
            }
            __syncthreads();
            // pooled -> out (same expression as pool2: gsums/cnt)
            const int np = nGraphs * 128;
            for (int i = tid; i < np; i += 256) {
                int g = i >> 7, cc = i & 127;
                out[(size_t)g * 128 + cc] = gsums[(size_t)g * 128 + cc] / cntS[g];
            }
            __syncthreads();
            // logits: same c-ascending serial accumulation as pool2
            const int nl = nGraphs * 32;
            for (int i = tid; i < nl; i += 256) {
                int g = i >> 5, kk = i & 31;
                float s = blin[kk];
                const float* po = out + (size_t)g * 128;
                for (int cc = 0; cc < 128; ++cc) s += po[cc] * wlin[cc * 32 + kk];
                out[(size_t)nGraphs * 128 + g * 32 + kk] = s;
            }
        }
    }
}

// ---------------------------------------------------------------------------

extern "C" void kernel_launch(void* const* d_in, const int* in_sizes, int n_in,
                              void* d_out, int out_size, void* d_ws, size_t ws_size,
                              hipStream_t stream) {
    const float* x     = (const float*)d_in[0];
    const int*   ei    = (const int*)d_in[1];
    const int*   batch = (const int*)d_in[2];
    const float* w1    = (const float*)d_in[3];
    const float* b1    = (const float*)d_in[4];
    const float* w2    = (const float*)d_in[5];
    const float* b2    = (const float*)d_in[6];
    const float* wlin  = (const float*)d_in[7];
    const float* blin  = (const float*)d_in[8];
    float* out = (float*)d_out;

    const int nNodes  = in_sizes[0] / 128;            // 50000
    const int nEdges  = in_sizes[1] / 2;              // 640000
    const int nLayers = in_sizes[3] / (128 * 128);    // 4
    const int nGraphs = out_size / 160;               // 64

    const int* srcArr = ei;
    const int* dstArr = ei + nEdges;

    // workspace layout (counts+gsums+donecnt adjacent -> single small memset)
    char* p = (char*)d_ws;
    int*   counts    = (int*)p;           p += (size_t)nNodes * 4;
    float* gsums     = (float*)p;         p += (size_t)nGraphs * 128 * 4;
    int*   donecnt   = (int*)p;           p += 4;
    int*   offsLocal = (int*)p;           p += (size_t)(nNodes + 1) * 4;
    int*   offsFinal = (int*)p;           p += (size_t)(nNodes + 1) * 4;
    int*   rank      = (int*)p;           p += (size_t)nEdges * 4;
    int*   partials  = (int*)p;           p += 256 * 4;
    int*   ssrc      = (int*)p;           p += (size_t)nEdges * 4;

    p = (char*)(((uintptr_t)p + 63) & ~(uintptr_t)63);
    const int wTotal = nLayers * 2 * 16384;           // frag-ordered split weights
    unsigned short* whf = (unsigned short*)p;  p += (size_t)wTotal * 2;
    unsigned short* wlf = (unsigned short*)p;  p += (size_t)wTotal * 2;

    p = (char*)(((uintptr_t)p + 63) & ~(uintptr_t)63);
    __half* xh   = (__half*)p;            p += (size_t)nNodes * 128 * 2;
    __half* bufA = (__half*)p;            p += (size_t)nNodes * 128 * 2;
    __half* bufB = (__half*)p;

    const size_t zeroBytes = ((size_t)nNodes + (size_t)nGraphs * 128 + 1) * 4;
    hipMemsetAsync(d_ws, 0, zeroBytes, stream);

    const int eb = (nEdges + 255) / 256;
    const int nb = (nNodes + 255) / 256;     // 196 chunks (<= 256 required)

    gin_build1<<<eb, 256, 0, stream>>>(dstArr, nEdges, counts, rank, w1, w2,
                                       whf, wlf, wTotal, x, xh, nNodes);
    gin_scanA<<<nb, 256, 0, stream>>>(counts, offsLocal, partials, nNodes);
    gin_scatfuse<<<eb, 256, 0, stream>>>(srcArr, dstArr, rank, nEdges,
                                         offsLocal, partials, nb,
                                         offsFinal, ssrc, nNodes);

    const int lb = (nNodes + TM - 1) / TM;
    const __half* hin = xh;
    __half* bufs[2] = {bufA, bufB};
    for (int L = 0; L < nLayers; ++L) {
        int last = (L == nLayers - 1);
        __half* hout = bufs[L & 1];
        gin_layer<<<lb, 256, 0, stream>>>(hin, offsFinal, ssrc, whf, wlf, 2 * L,
                                          b1 + (size_t)L * 128, b2 + (size_t)L * 128,
                                          hout, batch, gsums, donecnt,
                                          wlin, blin, out, nGraphs,
                                          nNodes, last);
        hin = hout;
    }
}

// Round 10
// 298.919 us; speedup vs baseline: 1.6739x; 1.6739x over previous
//
#include <hip/hip_runtime.h>
#include <hip/hip_fp16.h>

// ---------------------------------------------------------------------------
// GIN forward: 4x [agg(sum) -> Linear+ReLU -> Linear (+ReLU)] -> mean-pool -> head
// N_NODES=50000, N_EDGES=640000, D=128, N_GRAPHS=64, N_CLASSES=32
// R22: best-known config assembled from verified pieces:
//      - compact counts (R21: padded counts polluted L3, layer FETCH 91->65MB)
//      - rank-based atomic-free scatter + scanB(+)scatter fusion (R19/R20)
//      - EXACT R14 gin_layer (43.2us/layer, L2/L3 random-gather ceiling),
//        slim signature (VGPR 36), separate gin_pool2 (R21's last-block head
//        fusion created a 157us one-block serial tail -- reverted).
// ---------------------------------------------------------------------------

typedef short short8 __attribute__((ext_vector_type(8)));
typedef float floatx4 __attribute__((ext_vector_type(4)));

#define TM 32
#define ZSTRIDE 136   // shorts per row (128 + 8 pad); rows 16B-aligned

__device__ __forceinline__ unsigned short f2bf(float x) {
    unsigned int u = __float_as_uint(x);
    u += 0x7fffu + ((u >> 16) & 1u);          // RNE
    return (unsigned short)(u >> 16);
}
__device__ __forceinline__ float bf2f(unsigned short h) {
    return __uint_as_float(((unsigned int)h) << 16);
}

// fp16 row load: row id, this lane's 4-byte (2-col) slice; fp32 unpack
__device__ __forceinline__ float2 ldrowh(const char* __restrict__ base,
                                         int id, unsigned laneoff) {
    __half2 h = *(const __half2*)(base + ((unsigned)id << 8) + laneoff);
    return __half22float2(h);
}

// ---------------- build 1: weight split + dst histogram(+rank) + x->fp16 -----
// Wf[mat][kc(4)][ct(8)][lane(64)][j(8)] = W[kc*32+(lane>>4)*8+j][ct*16+(lane&15)]

__global__ __launch_bounds__(256) void gin_build1(
    const int* __restrict__ dst, int nEdges, int* __restrict__ counts,
    int* __restrict__ rank,
    const float* __restrict__ w1, const float* __restrict__ w2,
    unsigned short* __restrict__ whf, unsigned short* __restrict__ wlf, int wTotal,
    const float* __restrict__ x, __half* __restrict__ xh, int nNodes) {
    const int gsize = gridDim.x * 256;
    const int gtid = blockIdx.x * 256 + threadIdx.x;
    for (int idx = gtid; idx < wTotal; idx += gsize) {
        int mat  = idx >> 14;
        int rem  = idx & 16383;
        int kc   = rem >> 12;
        int ct   = (rem >> 9) & 7;
        int lane = (rem >> 3) & 63;
        int j    = rem & 7;
        int row = kc * 32 + (lane >> 4) * 8 + j;
        int col = ct * 16 + (lane & 15);
        int L = mat >> 1;
        const float* W = (mat & 1) ? (w2 + (size_t)L * 16384) : (w1 + (size_t)L * 16384);
        float v = W[row * 128 + col];
        unsigned short h = f2bf(v);
        unsigned short l = f2bf(v - bf2f(h));
        whf[idx] = h;
        wlf[idx] = l;
    }
    // x -> fp16 (one-time; layer 0 gathers from xh)
    const int total4 = nNodes * 32;                 // float4 quads
    for (int i = gtid; i < total4; i += gsize) {
        float4 v = ((const float4*)x)[i];
        union { __half2 h[2]; float2 f; } u;
        u.h[0] = __halves2half2(__float2half_rn(v.x), __float2half_rn(v.y));
        u.h[1] = __halves2half2(__float2half_rn(v.z), __float2half_rn(v.w));
        ((float2*)xh)[i] = u.f;
    }
    // histogram; returned old count = edge's rank within its dst segment
    for (int i = gtid; i < nEdges; i += gsize)
        rank[i] = atomicAdd(&counts[dst[i]], 1);
}

// ---------------- build 2a: per-chunk exclusive scan (chunk = 256) -----------

__global__ __launch_bounds__(256) void gin_scanA(const int* __restrict__ counts,
                                                 int* __restrict__ offsLocal,
                                                 int* __restrict__ partials, int n) {
    __shared__ int s[256];
    int t = threadIdx.x;
    int i = blockIdx.x * 256 + t;
    int v = (i < n) ? counts[i] : 0;
    s[t] = v;
    __syncthreads();
    for (int off = 1; off < 256; off <<= 1) {
        int u = (t >= off) ? s[t - off] : 0;
        __syncthreads();
        s[t] += u;
        __syncthreads();
    }
    if (i < n) offsLocal[i] = s[t] - v;        // block-local exclusive
    if (t == 255) partials[blockIdx.x] = s[255];
}

// ---------------- build 2b+3 fused: chunk bases + atomic-free scatter --------
// Every block redundantly scans partials[0..nb) in LDS for chunk bases.
// Scatter: pos = offsLocal[dst] + base[dst>>8] + rank. First nb blocks also
// write the finalized offsets into offsFinal (separate array -> no race).

__global__ __launch_bounds__(256) void gin_scatfuse(
    const int* __restrict__ src, const int* __restrict__ dst,
    const int* __restrict__ rank, int nEdges,
    const int* __restrict__ offsLocal, const int* __restrict__ partials,
    int nb, int* __restrict__ offsFinal, int* __restrict__ ssrc, int nNodes) {
    __shared__ int s[256];
    __shared__ int base[256];
    int t = threadIdx.x;
    s[t] = (t < nb) ? partials[t] : 0;
    __syncthreads();
    for (int off = 1; off < 256; off <<= 1) {
        int u = (t >= off) ? s[t - off] : 0;
        __syncthreads();
        s[t] += u;
        __syncthreads();
    }
    base[t] = (t > 0) ? s[t - 1] : 0;          // exclusive chunk bases
    __syncthreads();

    int i = blockIdx.x * 256 + t;
    if (i < nEdges) {
        int d = dst[i];
        int p = offsLocal[d] + base[d >> 8] + rank[i];
        ssrc[p] = src[i];
    }
    if (blockIdx.x < (unsigned)nb) {
        int j = blockIdx.x * 256 + t;
        if (j < nNodes) offsFinal[j] = offsLocal[j] + base[blockIdx.x];
        if (j == 0) offsFinal[nNodes] = nEdges;
    }
}

// ---------------- fused layer: agg -> MLP (TM=32, 256 thr, 4 waves) ----------
// EXACT R14 structure (best measured). Wave w gathers rows w*8..w*8+7
// (2-node interleave, 8 fp16 row-loads in flight, fp32 accumulate), then
// owns coltiles 2w,2w+1 over both rowgroups (A-frag reused x2). z / y1 live
// as bf16 hi/lo LDS planes (stride 136 shorts). Last layer pools into gsums.

__global__ __launch_bounds__(256) void gin_layer(const __half* __restrict__ hin,
                                                 const int* __restrict__ offs,
                                                 const int* __restrict__ ssrc,
                                                 const unsigned short* __restrict__ whf,
                                                 const unsigned short* __restrict__ wlf,
                                                 int matBase,
                                                 const float* __restrict__ b1p,
                                                 const float* __restrict__ b2p,
                                                 __half* __restrict__ hout,
                                                 const int* __restrict__ batch,
                                                 float* __restrict__ gsums,
                                                 int nNodes, int lastLayer) {
    __shared__ unsigned short smem[2 * TM * ZSTRIDE];   // hi plane, lo plane
    unsigned short* zh = smem;
    unsigned short* zl = smem + TM * ZSTRIDE;
    const int tid = threadIdx.x;
    const int w = tid >> 6, lane = tid & 63;
    const int lo4 = lane & 15, hi4 = lane >> 4;
    const int rowbase = blockIdx.x * TM;
    const char* hbase = (const char*)hin;
    const unsigned laneoff = (unsigned)lane * 4u;

    // ---- gather phase: wave w computes z rows w*8..w*8+7, 2 interleaved
    const int gbase = rowbase + w * 8;
#pragma unroll
    for (int pp = 0; pp < 4; ++pp) {
        int nA = gbase + 2 * pp, nB = nA + 1;
        bool okA = nA < nNodes, okB = nB < nNodes;
        float2 aA = make_float2(0.f, 0.f), aB = make_float2(0.f, 0.f);
        if (okA) aA = ldrowh(hbase, nA, laneoff);
        if (okB) aB = ldrowh(hbase, nB, laneoff);
        int eA = okA ? offs[nA] : 0, endA = okA ? offs[nA + 1] : 0;
        int eB = okB ? offs[nB] : 0, endB = okB ? offs[nB + 1] : 0;

        while (eA + 4 <= endA && eB + 4 <= endB) {
            int sA0 = ssrc[eA], sA1 = ssrc[eA + 1], sA2 = ssrc[eA + 2], sA3 = ssrc[eA + 3];
            int sB0 = ssrc[eB], sB1 = ssrc[eB + 1], sB2 = ssrc[eB + 2], sB3 = ssrc[eB + 3];
            float2 vA0 = ldrowh(hbase, sA0, laneoff);
            float2 vA1 = ldrowh(hbase, sA1, laneoff);
            float2 vA2 = ldrowh(hbase, sA2, laneoff);
            float2 vA3 = ldrowh(hbase, sA3, laneoff);
            float2 vB0 = ldrowh(hbase, sB0, laneoff);
            float2 vB1 = ldrowh(hbase, sB1, laneoff);
            float2 vB2 = ldrowh(hbase, sB2, laneoff);
            float2 vB3 = ldrowh(hbase, sB3, laneoff);
            aA.x += (vA0.x + vA1.x) + (vA2.x + vA3.x);
            aA.y += (vA0.y + vA1.y) + (vA2.y + vA3.y);
            aB.x += (vB0.x + vB1.x) + (vB2.x + vB3.x);
            aB.y += (vB0.y + vB1.y) + (vB2.y + vB3.y);
            eA += 4; eB += 4;
        }
        for (; eA + 4 <= endA; eA += 4) {
            int s0 = ssrc[eA], s1 = ssrc[eA + 1], s2 = ssrc[eA + 2], s3 = ssrc[eA + 3];
            float2 v0 = ldrowh(hbase, s0, laneoff);
            float2 v1 = ldrowh(hbase, s1, laneoff);
            float2 v2 = ldrowh(hbase, s2, laneoff);
            float2 v3 = ldrowh(hbase, s3, laneoff);
            aA.x += (v0.x + v1.x) + (v2.x + v3.x);
            aA.y += (v0.y + v1.y) + (v2.y + v3.y);
        }
        for (; eA < endA; ++eA) {
            float2 v = ldrowh(hbase, ssrc[eA], laneoff);
            aA.x += v.x; aA.y += v.y;
        }
        for (; eB + 4 <= endB; eB += 4) {
            int s0 = ssrc[eB], s1 = ssrc[eB + 1], s2 = ssrc[eB + 2], s3 = ssrc[eB + 3];
            float2 v0 = ldrowh(hbase, s0, laneoff);
            float2 v1 = ldrowh(hbase, s1, laneoff);
            float2 v2 = ldrowh(hbase, s2, laneoff);
            float2 v3 = ldrowh(hbase, s3, laneoff);
            aB.x += (v0.x + v1.x) + (v2.x + v3.x);
            aB.y += (v0.y + v1.y) + (v2.y + v3.y);
        }
        for (; eB < endB; ++eB) {
            float2 v = ldrowh(hbase, ssrc[eB], laneoff);
            aB.x += v.x; aB.y += v.y;
        }
        // write z (cols 2*lane, 2*lane+1) as one u32 per plane per row
        int rA = nA - rowbase, rB = rA + 1;
        unsigned short hx = f2bf(aA.x), hy = f2bf(aA.y);
        ((unsigned int*)zh)[rA * (ZSTRIDE / 2) + lane] = (unsigned)hx | ((unsigned)hy << 16);
        ((unsigned int*)zl)[rA * (ZSTRIDE / 2) + lane] =
            (unsigned)f2bf(aA.x - bf2f(hx)) | ((unsigned)f2bf(aA.y - bf2f(hy)) << 16);
        hx = f2bf(aB.x); hy = f2bf(aB.y);
        ((unsigned int*)zh)[rB * (ZSTRIDE / 2) + lane] = (unsigned)hx | ((unsigned)hy << 16);
        ((unsigned int*)zl)[rB * (ZSTRIDE / 2) + lane] =
            (unsigned)f2bf(aB.x - bf2f(hx)) | ((unsigned)f2bf(aB.y - bf2f(hy)) << 16);
    }
    __syncthreads();

    // ---- MLP phase 1: y1 = relu(z @ W1 + b1); wave w owns coltiles 2w,2w+1
    floatx4 acc[2][2];
#pragma unroll
    for (int rg = 0; rg < 2; ++rg)
#pragma unroll
        for (int ct = 0; ct < 2; ++ct) acc[rg][ct] = (floatx4)0.f;

    for (int kc = 0; kc < 4; ++kc) {
        size_t o0 = ((((size_t)matBase * 4 + kc) * 8 + (2 * w)) * 64 + lane) * 8;
        size_t o1 = ((((size_t)matBase * 4 + kc) * 8 + (2 * w + 1)) * 64 + lane) * 8;
        short8 bh0 = *(const short8*)(whf + o0), bl0 = *(const short8*)(wlf + o0);
        short8 bh1 = *(const short8*)(whf + o1), bl1 = *(const short8*)(wlf + o1);
#pragma unroll
        for (int rg = 0; rg < 2; ++rg) {
            const int rbase = (rg * 16 + lo4) * ZSTRIDE + kc * 32 + hi4 * 8;
            short8 ah = *(const short8*)(zh + rbase);
            short8 al = *(const short8*)(zl + rbase);
            acc[rg][0] = __builtin_amdgcn_mfma_f32_16x16x32_bf16(ah, bh0, acc[rg][0], 0, 0, 0);
            acc[rg][0] = __builtin_amdgcn_mfma_f32_16x16x32_bf16(al, bh0, acc[rg][0], 0, 0, 0);
            acc[rg][0] = __builtin_amdgcn_mfma_f32_16x16x32_bf16(ah, bl0, acc[rg][0], 0, 0, 0);
            acc[rg][1] = __builtin_amdgcn_mfma_f32_16x16x32_bf16(ah, bh1, acc[rg][1], 0, 0, 0);
            acc[rg][1] = __builtin_amdgcn_mfma_f32_16x16x32_bf16(al, bh1, acc[rg][1], 0, 0, 0);
            acc[rg][1] = __builtin_amdgcn_mfma_f32_16x16x32_bf16(ah, bl1, acc[rg][1], 0, 0, 0);
        }
    }
    __syncthreads();   // all z reads done; planes reusable for y1

    // epilogue 1: bias + relu + split -> zh/zl (y1)
    float bb1_0 = b1p[w * 32 + lo4];
    float bb1_1 = b1p[w * 32 + 16 + lo4];
#pragma unroll
    for (int rg = 0; rg < 2; ++rg)
#pragma unroll
        for (int ct = 0; ct < 2; ++ct) {
            float bb = ct ? bb1_1 : bb1_0;
#pragma unroll
            for (int r = 0; r < 4; ++r) {
                float v = fmaxf(acc[rg][ct][r] + bb, 0.f);
                unsigned short h = f2bf(v);
                int idx = (rg * 16 + hi4 * 4 + r) * ZSTRIDE + w * 32 + ct * 16 + lo4;
                zh[idx] = h;
                zl[idx] = f2bf(v - bf2f(h));
            }
        }
    __syncthreads();

    // ---- MLP phase 2: h = y1 @ W2 + b2
#pragma unroll
    for (int rg = 0; rg < 2; ++rg)
#pragma unroll
        for (int ct = 0; ct < 2; ++ct) acc[rg][ct] = (floatx4)0.f;

    for (int kc = 0; kc < 4; ++kc) {
        size_t o0 = ((((size_t)(matBase + 1) * 4 + kc) * 8 + (2 * w)) * 64 + lane) * 8;
        size_t o1 = ((((size_t)(matBase + 1) * 4 + kc) * 8 + (2 * w + 1)) * 64 + lane) * 8;
        short8 bh0 = *(const short8*)(whf + o0), bl0 = *(const short8*)(wlf + o0);
        short8 bh1 = *(const short8*)(whf + o1), bl1 = *(const short8*)(wlf + o1);
#pragma unroll
        for (int rg = 0; rg < 2; ++rg) {
            const int rbase = (rg * 16 + lo4) * ZSTRIDE + kc * 32 + hi4 * 8;
            short8 ah = *(const short8*)(zh + rbase);
            short8 al = *(const short8*)(zl + rbase);
            acc[rg][0] = __builtin_amdgcn_mfma_f32_16x16x32_bf16(ah, bh0, acc[rg][0], 0, 0, 0);
            acc[rg][0] = __builtin_amdgcn_mfma_f32_16x16x32_bf16(al, bh0, acc[rg][0], 0, 0, 0);
            acc[rg][0] = __builtin_amdgcn_mfma_f32_16x16x32_bf16(ah, bl0, acc[rg][0], 0, 0, 0);
            acc[rg][1] = __builtin_amdgcn_mfma_f32_16x16x32_bf16(ah, bh1, acc[rg][1], 0, 0, 0);
            acc[rg][1] = __builtin_amdgcn_mfma_f32_16x16x32_bf16(al, bh1, acc[rg][1], 0, 0, 0);
            acc[rg][1] = __builtin_amdgcn_mfma_f32_16x16x32_bf16(ah, bl1, acc[rg][1], 0, 0, 0);
        }
    }

    float bb2_0 = b2p[w * 32 + lo4];
    float bb2_1 = b2p[w * 32 + 16 + lo4];

    if (!lastLayer) {
#pragma unroll
        for (int rg = 0; rg < 2; ++rg)
#pragma unroll
            for (int ct = 0; ct < 2; ++ct) {
                float bb = ct ? bb2_1 : bb2_0;
#pragma unroll
                for (int r = 0; r < 4; ++r) {
                    int row = rowbase + rg * 16 + hi4 * 4 + r;
                    if (row < nNodes) {
                        float v = fmaxf(acc[rg][ct][r] + bb, 0.f);
                        hout[(size_t)row * 128 + w * 32 + ct * 16 + lo4] = __float2half_rn(v);
                    }
                }
            }
    } else {
        // last layer: no relu; pool tile into gsums (h never hits HBM)
        __syncthreads();   // all y1 reads done; reuse smem as fp32 h (stride 132)
        float* zf = (float*)smem;
#pragma unroll
        for (int rg = 0; rg < 2; ++rg)
#pragma unroll
            for (int ct = 0; ct < 2; ++ct) {
                float bb = ct ? bb2_1 : bb2_0;
#pragma unroll
                for (int r = 0; r < 4; ++r)
                    zf[(rg * 16 + hi4 * 4 + r) * 132 + w * 32 + ct * 16 + lo4] =
                        acc[rg][ct][r] + bb;
            }
        __syncthreads();
        int c = tid & 127, half = tid >> 7;
        int rmax = nNodes - rowbase;
        if (rmax > TM) rmax = TM;
        float accp = 0.f;
        int gcur = -1;
        for (int r = half; r < rmax; r += 2) {
            int g = batch[rowbase + r];
            if (g != gcur) {
                if (gcur >= 0) atomicAdd(&gsums[gcur * 128 + c], accp);
                accp = 0.f;
                gcur = g;
            }
            accp += zf[r * 132 + c];
        }
        if (gcur >= 0) atomicAdd(&gsums[gcur * 128 + c], accp);
    }
}

// ---------------- finalize: divide by count + classifier head ----------------

__device__ __forceinline__ int lb_search(const int* __restrict__ a, int n, int key) {
    int lo = 0, hi = n;
    while (lo < hi) {
        int m = (lo + hi) >> 1;
        if (a[m] < key) lo = m + 1; else hi = m;
    }
    return lo;
}

__global__ __launch_bounds__(128) void gin_pool2(const float* __restrict__ gsums,
                                                 const int* __restrict__ batch, int nNodes,
                                                 const float* __restrict__ wlin,
                                                 const float* __restrict__ blin,
                                                 float* __restrict__ out, int nGraphs) {
    __shared__ float sp[128];
    int g = blockIdx.x;
    int t = threadIdx.x;
    int start = lb_search(batch, nNodes, g);
    int end   = lb_search(batch, nNodes, g + 1);
    float cnt = (float)(end - start);
    float p = gsums[(size_t)g * 128 + t] / fmaxf(cnt, 1.0f);
    out[(size_t)g * 128 + t] = p;
    sp[t] = p;
    __syncthreads();
    if (t < 32) {
        float s = blin[t];
        for (int k = 0; k < 128; ++k) s += sp[k] * wlin[k * 32 + t];
        out[(size_t)nGraphs * 128 + g * 32 + t] = s;
    }
}

// ---------------------------------------------------------------------------

extern "C" void kernel_launch(void* const* d_in, const int* in_sizes, int n_in,
                              void* d_out, int out_size, void* d_ws, size_t ws_size,
                              hipStream_t stream) {
    const float* x     = (const float*)d_in[0];
    const int*   ei    = (const int*)d_in[1];
    const int*   batch = (const int*)d_in[2];
    const float* w1    = (const float*)d_in[3];
    const float* b1    = (const float*)d_in[4];
    const float* w2    = (const float*)d_in[5];
    const float* b2    = (const float*)d_in[6];
    const float* wlin  = (const float*)d_in[7];
    const float* blin  = (const float*)d_in[8];
    float* out = (float*)d_out;

    const int nNodes  = in_sizes[0] / 128;            // 50000
    const int nEdges  = in_sizes[1] / 2;              // 640000
    const int nLayers = in_sizes[3] / (128 * 128);    // 4
    const int nGraphs = out_size / 160;               // 64

    const int* srcArr = ei;
    const int* dstArr = ei + nEdges;

    // workspace layout (counts+gsums adjacent -> single small memset)
    char* p = (char*)d_ws;
    int*   counts    = (int*)p;           p += (size_t)nNodes * 4;
    float* gsums     = (float*)p;         p += (size_t)nGraphs * 128 * 4;
    int*   offsLocal = (int*)p;           p += (size_t)(nNodes + 1) * 4;
    int*   offsFinal = (int*)p;           p += (size_t)(nNodes + 1) * 4;
    int*   rank      = (int*)p;           p += (size_t)nEdges * 4;
    int*   partials  = (int*)p;           p += 256 * 4;
    int*   ssrc      = (int*)p;           p += (size_t)nEdges * 4;

    p = (char*)(((uintptr_t)p + 63) & ~(uintptr_t)63);
    const int wTotal = nLayers * 2 * 16384;           // frag-ordered split weights
    unsigned short* whf = (unsigned short*)p;  p += (size_t)wTotal * 2;
    unsigned short* wlf = (unsigned short*)p;  p += (size_t)wTotal * 2;

    p = (char*)(((uintptr_t)p + 63) & ~(uintptr_t)63);
    __half* xh   = (__half*)p;            p += (size_t)nNodes * 128 * 2;
    __half* bufA = (__half*)p;            p += (size_t)nNodes * 128 * 2;
    __half* bufB = (__half*)p;

    const size_t zeroBytes = ((size_t)nNodes + (size_t)nGraphs * 128) * 4;
    hipMemsetAsync(d_ws, 0, zeroBytes, stream);

    const int eb = (nEdges + 255) / 256;
    const int nb = (nNodes + 255) / 256;     // 196 chunks (<= 256 required)

    gin_build1<<<eb, 256, 0, stream>>>(dstArr, nEdges, counts, rank, w1, w2,
                                       whf, wlf, wTotal, x, xh, nNodes);
    gin_scanA<<<nb, 256, 0, stream>>>(counts, offsLocal, partials, nNodes);
    gin_scatfuse<<<eb, 256, 0, stream>>>(srcArr, dstArr, rank, nEdges,
                                         offsLocal, partials, nb,
                                         offsFinal, ssrc, nNodes);

    const int lb = (nNodes + TM - 1) / TM;
    const __half* hin = xh;
    __half* bufs[2] = {bufA, bufB};
    for (int L = 0; L < nLayers; ++L) {
        int last = (L == nLayers - 1);
        __half* hout = bufs[L & 1];
        gin_layer<<<lb, 256, 0, stream>>>(hin, offsFinal, ssrc, whf, wlf, 2 * L,
                                          b1 + (size_t)L * 128, b2 + (size_t)L * 128,
                                          hout, batch, gsums, nNodes, last);
        hin = hout;
    }
    gin_pool2<<<nGraphs, 128, 0, stream>>>(gsums, batch, nNodes, wlin, blin, out, nGraphs);
}